// Round 1
// baseline (3412.535 us; speedup 1.0000x reference)
//
#include <hip/hip_runtime.h>
#include <hip/hip_bf16.h>
#include <cstdint>
#include <cstddef>

#define B_ALL 256
#define T_LEN 512
#define D_INP 64
#define HD    128
#define G4    512            // 4*H
#define NC    12
#define BCH   128            // batch per chunk
#define ROWS  (BCH * T_LEN)  // 65536 rows per chunk

// ---------- helpers ----------
__device__ __forceinline__ float bf2f(unsigned short u) {
    union { unsigned int i; float f; } v; v.i = ((unsigned int)u) << 16; return v.f;
}
__device__ __forceinline__ unsigned short f2bf(float f) {
    union { float f; unsigned int i; } v; v.f = f;
    unsigned int r = v.i + 0x7FFFu + ((v.i >> 16) & 1u);  // round-nearest-even
    return (unsigned short)(r >> 16);
}
__device__ __forceinline__ float sigf(float x) { return 1.0f / (1.0f + __expf(-x)); }
__device__ __forceinline__ float tanh_f(float x) {
    float xx = fminf(15.0f, fmaxf(-15.0f, x));
    float e = __expf(2.0f * xx);
    return (e - 1.0f) / (e + 1.0f);
}

__device__ __forceinline__ float4 loadA4(const float* p) { return *(const float4*)p; }
__device__ __forceinline__ float4 loadA4(const unsigned short* p) {
    ushort4 u = *(const ushort4*)p;  // 8B aligned
    return make_float4(bf2f(u.x), bf2f(u.y), bf2f(u.z), bf2f(u.w));
}

// ---------- gates GEMM: out[r][c] = bias[c] + sum_k A[r][k] * W[c][k] ----------
// out is bf16 [rows][1024]; c = dir*512 + g. Tile 128x128, 256 threads, 8x8/thread.
// Skips blocks whose entire 128-row span has t >= len[b] (outputs never consumed).
template <typename TA>
__global__ __launch_bounds__(256)
void gates_gemm(const TA* __restrict__ A, const float* __restrict__ W,
                const float* __restrict__ bias, const int* __restrict__ lens,
                unsigned short* __restrict__ out, int K)
{
    int row0 = blockIdx.x * 128;
    int col0 = blockIdx.y * 128;
    int bl = row0 >> 9;            // T_LEN = 512 rows per batch element
    int t0 = row0 & (T_LEN - 1);
    if (t0 >= lens[bl]) return;    // whole tile masked -> never read downstream

    __shared__ float As[32][130];  // [k][row], stride 130: conflict-light, 8B aligned
    __shared__ float Bs[32][130];

    int tid = threadIdx.x;
    int tx = tid & 15;             // col group
    int ty = tid >> 4;             // row group
    int lr = tid >> 3;             // 0..31 staging row
    int lk = (tid & 7) * 4;        // 0,4,...,28 staging k

    float acc[8][8];
#pragma unroll
    for (int i = 0; i < 8; ++i)
#pragma unroll
        for (int j = 0; j < 8; ++j) acc[i][j] = 0.0f;

    for (int kt = 0; kt < K; kt += 32) {
#pragma unroll
        for (int rr = 0; rr < 128; rr += 32) {
            int r = rr + lr;
            float4 v = loadA4(A + (size_t)(row0 + r) * K + kt + lk);
            As[lk + 0][r] = v.x; As[lk + 1][r] = v.y;
            As[lk + 2][r] = v.z; As[lk + 3][r] = v.w;
        }
#pragma unroll
        for (int rr = 0; rr < 128; rr += 32) {
            int c = rr + lr;
            float4 v = *(const float4*)(W + (size_t)(col0 + c) * K + kt + lk);
            Bs[lk + 0][c] = v.x; Bs[lk + 1][c] = v.y;
            Bs[lk + 2][c] = v.z; Bs[lk + 3][c] = v.w;
        }
        __syncthreads();
#pragma unroll 8
        for (int kk = 0; kk < 32; ++kk) {
            float a[8], b[8];
#pragma unroll
            for (int q = 0; q < 4; ++q) {
                float2 t = *(const float2*)&As[kk][ty * 8 + 2 * q];
                a[2 * q] = t.x; a[2 * q + 1] = t.y;
                float2 u = *(const float2*)&Bs[kk][tx * 8 + 2 * q];
                b[2 * q] = u.x; b[2 * q + 1] = u.y;
            }
#pragma unroll
            for (int i = 0; i < 8; ++i)
#pragma unroll
                for (int j = 0; j < 8; ++j) acc[i][j] += a[i] * b[j];
        }
        __syncthreads();
    }

    float bj[8];
#pragma unroll
    for (int j = 0; j < 8; ++j) bj[j] = bias[col0 + tx * 8 + j];
#pragma unroll
    for (int i = 0; i < 8; ++i) {
        size_t base = (size_t)(row0 + ty * 8 + i) * 1024 + col0 + tx * 8;
        ushort4 p0, p1;
        p0.x = f2bf(acc[i][0] + bj[0]); p0.y = f2bf(acc[i][1] + bj[1]);
        p0.z = f2bf(acc[i][2] + bj[2]); p0.w = f2bf(acc[i][3] + bj[3]);
        p1.x = f2bf(acc[i][4] + bj[4]); p1.y = f2bf(acc[i][5] + bj[5]);
        p1.z = f2bf(acc[i][6] + bj[6]); p1.w = f2bf(acc[i][7] + bj[7]);
        *(ushort4*)&out[base] = p0;
        *(ushort4*)&out[base + 4] = p1;
    }
}

// ---------- LSTM recurrence: one block per (dir, batch-element) ----------
// 512 threads; thread j owns gate row j with Whh[j][0:128] in registers.
// h broadcast through LDS each step; loop stops at len[b] (mask => freeze + zero).
__global__ __launch_bounds__(512)
void lstm_rec(const unsigned short* __restrict__ xg,   // [ROWS][1024]
              const float* __restrict__ Whh,           // [2][512][128]
              const int* __restrict__ lens,            // chunk-offset
              unsigned short* __restrict__ hs,         // [ROWS][256] or null
              float* __restrict__ hTf, float* __restrict__ hTb,
              int bOff)
{
    int dir = blockIdx.x >> 7;   // 128 batch per chunk
    int bl  = blockIdx.x & 127;
    int L   = lens[bl];
    int j   = threadIdx.x;

    __shared__ float h_s[HD];
    __shared__ float g_s[G4];

    float w[HD];
    const float* wrow = Whh + ((size_t)dir * G4 + j) * HD;
#pragma unroll
    for (int k = 0; k < HD; k += 4) {
        float4 v = *(const float4*)(wrow + k);
        w[k] = v.x; w[k + 1] = v.y; w[k + 2] = v.z; w[k + 3] = v.w;
    }

    if (j < HD) h_s[j] = 0.0f;
    float c = 0.0f;
    __syncthreads();

    for (int t = 0; t < L; ++t) {
        int tt = dir ? (L - 1 - t) : t;   // backward runs reversed valid prefix
        size_t rowoff = (size_t)(bl * T_LEN + tt) * 1024 + dir * G4;
        float g = bf2f(xg[rowoff + j]);
#pragma unroll
        for (int k = 0; k < HD; k += 4) {
            float4 h4 = *(const float4*)&h_s[k];   // wave-uniform broadcast read
            g += w[k] * h4.x + w[k + 1] * h4.y + w[k + 2] * h4.z + w[k + 3] * h4.w;
        }
        g_s[j] = g;
        __syncthreads();
        if (j < HD) {
            float ig = sigf(g_s[j]);
            float fg = sigf(g_s[j + 128]);
            float gg = tanh_f(g_s[j + 256]);
            float og = sigf(g_s[j + 384]);
            c = fg * c + ig * gg;
            float hn = og * tanh_f(c);
            h_s[j] = hn;
            if (hs) hs[(size_t)(bl * T_LEN + tt) * 256 + dir * HD + j] = f2bf(hn);
        }
        __syncthreads();
    }
    if (hTf && j < HD) {
        (dir ? hTb : hTf)[(size_t)(bOff + bl) * HD + j] = h_s[j];
    }
}

// ---------- final FC + log_softmax: h = [hT_b, hT_f] ----------
__global__ __launch_bounds__(256)
void fc_lsm(const float* __restrict__ hTf, const float* __restrict__ hTb,
            const float* __restrict__ Wfc, const float* __restrict__ bfc,
            float* __restrict__ out)
{
    int b = threadIdx.x;
    const float* hb = hTb + (size_t)b * HD;
    const float* hf = hTf + (size_t)b * HD;
    float l[NC];
#pragma unroll
    for (int cc = 0; cc < NC; ++cc) {
        const float* wr = Wfc + cc * 256;
        float acc = bfc[cc];
        for (int k = 0; k < HD; k += 4) {
            acc += hb[k] * wr[k] + hb[k + 1] * wr[k + 1]
                 + hb[k + 2] * wr[k + 2] + hb[k + 3] * wr[k + 3];
            acc += hf[k] * wr[128 + k] + hf[k + 1] * wr[128 + k + 1]
                 + hf[k + 2] * wr[128 + k + 2] + hf[k + 3] * wr[128 + k + 3];
        }
        l[cc] = acc;
    }
    float m = l[0];
#pragma unroll
    for (int cc = 1; cc < NC; ++cc) m = fmaxf(m, l[cc]);
    float s = 0.0f;
#pragma unroll
    for (int cc = 0; cc < NC; ++cc) s += __expf(l[cc] - m);
    float lg = m + logf(s);
#pragma unroll
    for (int cc = 0; cc < NC; ++cc) out[(size_t)b * NC + cc] = l[cc] - lg;
}

extern "C" void kernel_launch(void* const* d_in, const int* in_sizes, int n_in,
                              void* d_out, int out_size, void* d_ws, size_t ws_size,
                              hipStream_t stream)
{
    const float* X    = (const float*)d_in[0];
    const int*   len  = (const int*)d_in[1];
    const float* Wih0 = (const float*)d_in[2];   // (2,512,64)  -> (1024,64)
    const float* Whh0 = (const float*)d_in[3];   // (2,512,128)
    const float* b0   = (const float*)d_in[4];   // (2,512) -> (1024)
    const float* Wih1 = (const float*)d_in[5];   // (2,512,256) -> (1024,256)
    const float* Whh1 = (const float*)d_in[6];
    const float* b1   = (const float*)d_in[7];
    const float* Wfc  = (const float*)d_in[8];   // (12,256)
    const float* bfc  = (const float*)d_in[9];   // (12)
    float* out = (float*)d_out;

    char* ws = (char*)d_ws;
    unsigned short* xg = (unsigned short*)ws;                              // ROWS*1024 bf16
    unsigned short* h1 = (unsigned short*)(ws + (size_t)ROWS * 1024 * 2);  // ROWS*256 bf16
    float* hTf = (float*)(ws + (size_t)ROWS * 1024 * 2 + (size_t)ROWS * 256 * 2);
    float* hTb = hTf + (size_t)B_ALL * HD;

    dim3 blk(256);
    for (int ch = 0; ch < 2; ++ch) {
        const int* lc = len + ch * BCH;
        const float* Xc = X + (size_t)ch * BCH * T_LEN * D_INP;

        gates_gemm<float><<<dim3(ROWS / 128, 1024 / 128), blk, 0, stream>>>(
            Xc, Wih0, b0, lc, xg, D_INP);
        lstm_rec<<<2 * BCH, 512, 0, stream>>>(xg, Whh0, lc, h1, nullptr, nullptr, 0);
        gates_gemm<unsigned short><<<dim3(ROWS / 128, 1024 / 128), blk, 0, stream>>>(
            h1, Wih1, b1, lc, xg, 2 * HD);
        lstm_rec<<<2 * BCH, 512, 0, stream>>>(xg, Whh1, lc, nullptr, hTf, hTb, ch * BCH);
    }
    fc_lsm<<<1, 256, 0, stream>>>(hTf, hTb, Wfc, bfc, out);
}